// Round 5
// baseline (344.794 us; speedup 1.0000x reference)
//
#include <hip/hip_runtime.h>
#include <hip/hip_bf16.h>

typedef unsigned short u16;
typedef __bf16 bf16x8 __attribute__((ext_vector_type(8)));
typedef u16 u16x8 __attribute__((ext_vector_type(8)));
typedef float f32x4 __attribute__((ext_vector_type(4)));

__device__ __forceinline__ float bf2f(u16 u) {
  union { unsigned u32; float f; } c; c.u32 = ((unsigned)u) << 16; return c.f;
}
__device__ __forceinline__ u16 f2bf(float f) {
  union { float f; unsigned u32; } c; c.f = f;
  unsigned r = c.u32 + 0x7FFFu + ((c.u32 >> 16) & 1u);
  return (u16)(r >> 16);
}

#define GLD16(gp, lp) __builtin_amdgcn_global_load_lds( \
    (const __attribute__((address_space(1))) void*)(gp), \
    (__attribute__((address_space(3))) void*)(lp), 16, 0, 0)

// ---------------------------------------------------------------------------
// fp32 -> bf16 cast, 4 elems/thread.
// ---------------------------------------------------------------------------
__global__ __launch_bounds__(256)
void cast_f32_bf16_kernel(const float* __restrict__ in, u16* __restrict__ out,
                          int n4) {
  const int i = (blockIdx.x * 256 + threadIdx.x) * 4;
  if (i < n4) {
    float4 v = *(const float4*)(in + i);
    ushort4 o;
    o.x = f2bf(v.x); o.y = f2bf(v.y); o.z = f2bf(v.z); o.w = f2bf(v.w);
    *(ushort4*)(out + i) = o;
  }
}

// ---------------------------------------------------------------------------
// Pipelined GEMM: C[M,N] = A[M,K] @ B[N,K]^T, bf16 in, fp32 accum, bf16 or
// fp32(+bias) out. 128x128 tile, BK=32, 4 waves, global_load_lds width-16.
// T4 pipeline: 3 LDS buffers, stage K-tile t+2 while computing t, counted
// s_waitcnt vmcnt(4) (t+2's 4 loads stay in flight across the barrier),
// ONE raw s_barrier per K-step. K must be divisible by 96 (768 = 24*32 ok).
// Race audit: buf[(t+2)%3] == buf[(t-1)%3]; its last readers (iter t-1)
// all passed barrier(t-1) before any iter-t stage issue. Reads of buf[t%3]
// are covered by iter t-1's vmcnt(4)+barrier.
// ---------------------------------------------------------------------------
template<int BIAS, int OUTF32>
__global__ __launch_bounds__(256)
void gemm_bt_kernel(const u16* __restrict__ A, const u16* __restrict__ B,
                    void* __restrict__ Cv, const float* __restrict__ bias,
                    int M, int N, int K, int nbn) {
  __shared__ alignas(16) u16 As[3][128][32];   // 24 KB
  __shared__ alignas(16) u16 Bs[3][128][32];   // 24 KB
  const int tid = threadIdx.x;
  const int l = tid & 63, w = tid >> 6;
  const int lane16 = l & 15, lg = l >> 4;
  const int wr = w >> 1, wc = w & 1;
  // bijective XCD swizzle (gridDim.x % 8 == 0 by construction)
  const int cpx = gridDim.x >> 3;
  const int swz = (blockIdx.x & 7) * cpx + (blockIdx.x >> 3);
  const int bm = swz / nbn, bn = swz - bm * nbn;

  const f32x4 zero = {0.f, 0.f, 0.f, 0.f};
  f32x4 acc[4][4];
#pragma unroll
  for (int i = 0; i < 4; ++i)
#pragma unroll
    for (int j = 0; j < 4; ++j) acc[i][j] = zero;

  const int r0 = tid >> 2, e0 = (tid & 3) * 8;
  const u16* Ap0 = A + (size_t)(bm * 128 + r0) * K + e0;
  const u16* Ap1 = A + (size_t)(bm * 128 + r0 + 64) * K + e0;
  const u16* Bp0 = B + (size_t)(bn * 128 + r0) * K + e0;
  const u16* Bp1 = B + (size_t)(bn * 128 + r0 + 64) * K + e0;
  const int nt = K >> 5;   // 24

#define STAGE(T, CB) do {                                             \
    const int kk = (T) * 32;                                          \
    GLD16(Ap0 + kk, (char*)&As[CB][0][0] + w * 1024);                 \
    GLD16(Ap1 + kk, (char*)&As[CB][0][0] + 4096 + w * 1024);          \
    GLD16(Bp0 + kk, (char*)&Bs[CB][0][0] + w * 1024);                 \
    GLD16(Bp1 + kk, (char*)&Bs[CB][0][0] + 4096 + w * 1024);          \
  } while (0)

#define COMPUTE(CB) do {                                              \
    bf16x8 af[4], bfr[4];                                             \
    _Pragma("unroll")                                                 \
    for (int i = 0; i < 4; ++i)                                       \
      af[i] = *(const bf16x8*)&As[CB][wr * 64 + i * 16 + lane16][lg * 8]; \
    _Pragma("unroll")                                                 \
    for (int j = 0; j < 4; ++j)                                       \
      bfr[j] = *(const bf16x8*)&Bs[CB][wc * 64 + j * 16 + lane16][lg * 8]; \
    __builtin_amdgcn_s_setprio(1);                                    \
    _Pragma("unroll")                                                 \
    for (int i = 0; i < 4; ++i)                                       \
      _Pragma("unroll")                                               \
      for (int j = 0; j < 4; ++j)                                     \
        acc[i][j] = __builtin_amdgcn_mfma_f32_16x16x32_bf16(af[i], bfr[j], acc[i][j], 0, 0, 0); \
    __builtin_amdgcn_s_setprio(0);                                    \
  } while (0)

#define VMC4  asm volatile("s_waitcnt vmcnt(4)" ::: "memory")
#define VMC0  asm volatile("s_waitcnt vmcnt(0)" ::: "memory")
#define BAR   asm volatile("s_barrier" ::: "memory")

  // prologue: t0 -> buf0, t1 -> buf1; wait t0 landed (4 of 8 drained)
  STAGE(0, 0);
  STAGE(1, 1);
  VMC4; BAR;

  // steady state: iters 0 .. nt-4 (stage t+2, vmcnt(4))
  for (int t = 0; t < nt - 3; t += 3) {
    STAGE(t + 2, 2); COMPUTE(0); VMC4; BAR;
    STAGE(t + 3, 0); COMPUTE(1); VMC4; BAR;
    STAGE(t + 4, 1); COMPUTE(2); VMC4; BAR;
  }
  // tail: t = nt-3 (stage nt-1 -> buf (nt-1)%3 = 2), nt-2, nt-1
  STAGE(nt - 1, 2); COMPUTE(0); VMC4; BAR;   // drains (nt-2)'s loads
  COMPUTE(1); VMC0; BAR;                     // drains (nt-1)'s loads
  COMPUTE(2);

#undef STAGE
#undef COMPUTE
#undef VMC4
#undef VMC0
#undef BAR

  // epilogue: D layout col = lane&15, row = (lane>>4)*4 + reg
  const int row0 = bm * 128 + wr * 64, col0 = bn * 128 + wc * 64;
#pragma unroll
  for (int i = 0; i < 4; ++i) {
#pragma unroll
    for (int j = 0; j < 4; ++j) {
      const int col = col0 + j * 16 + lane16;
      const float badd = BIAS ? bias[col] : 0.f;
      const int rbase = row0 + i * 16 + lg * 4;
#pragma unroll
      for (int r = 0; r < 4; ++r) {
        const float v = acc[i][j][r] + badd;
        if (OUTF32) ((float*)Cv)[(size_t)(rbase + r) * N + col] = v;
        else        ((u16*)Cv)[(size_t)(rbase + r) * N + col] = f2bf(v);
      }
    }
  }
}

// ---------------------------------------------------------------------------
// XCA attention core (unchanged from round 4 — passed). One block per (b,h).
// ---------------------------------------------------------------------------
__global__ __launch_bounds__(256)
void xca_attn_kernel(const u16* __restrict__ qkv,
                     const float* __restrict__ temperature,
                     u16* __restrict__ aout) {
  const int tid = threadIdx.x;
  const int l = tid & 63, w = tid >> 6;
  const int lane16 = l & 15, lg = l >> 4;
  const int bh = blockIdx.x, b = bh >> 4, h = bh & 15;
  const size_t base = (size_t)b * 1024 * 2304 + (size_t)h * 48;

  __shared__ alignas(16) u16 qt[4][48][32];
  __shared__ alignas(16) u16 kt[4][48][32];
  __shared__ alignas(16) float attn_raw[48][48];
  __shared__ alignas(16) u16 attn_bf[48][64];
  __shared__ float sqs[2][48];
  __shared__ float rn[2][48];

  for (int i = tid; i < 48 * 48; i += 256) ((float*)attn_raw)[i] = 0.f;
  if (tid < 96) ((float*)sqs)[tid] = 0.f;
  __syncthreads();

  const f32x4 zero = {0.f, 0.f, 0.f, 0.f};
  f32x4 pqk[3][3], pqq[3], pkk[3];
#pragma unroll
  for (int i = 0; i < 3; ++i) {
    pqq[i] = zero; pkk[i] = zero;
#pragma unroll
    for (int j = 0; j < 3; ++j) pqk[i][j] = zero;
  }

  for (int s = 0; s < 8; ++s) {
    const int n0 = (s * 4 + w) * 32;
#pragma unroll
    for (int t0 = 0; t0 < 3; ++t0) {
      const int t = t0 * 64 + l;
      const int mat = t >= 96;
      const int tt = t - mat * 96;
      const int d0 = (tt % 12) * 4, nl0 = (tt / 12) * 4;
      const u16* src = qkv + base + (size_t)(n0 + nl0) * 2304 + mat * 768 + d0;
      ushort4 r0 = *(const ushort4*)(src);
      ushort4 r1 = *(const ushort4*)(src + 2304);
      ushort4 r2 = *(const ushort4*)(src + 4608);
      ushort4 r3 = *(const ushort4*)(src + 6912);
      u16 (*dst)[32] = mat ? kt[w] : qt[w];
      ushort4 c;
      c.x = r0.x; c.y = r1.x; c.z = r2.x; c.w = r3.x; *(ushort4*)&dst[d0 + 0][nl0] = c;
      c.x = r0.y; c.y = r1.y; c.z = r2.y; c.w = r3.y; *(ushort4*)&dst[d0 + 1][nl0] = c;
      c.x = r0.z; c.y = r1.z; c.z = r2.z; c.w = r3.z; *(ushort4*)&dst[d0 + 2][nl0] = c;
      c.x = r0.w; c.y = r1.w; c.z = r2.w; c.w = r3.w; *(ushort4*)&dst[d0 + 3][nl0] = c;
    }
    asm volatile("s_waitcnt lgkmcnt(0)" ::: "memory");
    __builtin_amdgcn_sched_barrier(0);

    bf16x8 qf[3], kf[3];
#pragma unroll
    for (int i = 0; i < 3; ++i)
      qf[i] = *(const bf16x8*)&qt[w][i * 16 + lane16][lg * 8];
#pragma unroll
    for (int j = 0; j < 3; ++j)
      kf[j] = *(const bf16x8*)&kt[w][j * 16 + lane16][lg * 8];
#pragma unroll
    for (int i = 0; i < 3; ++i)
#pragma unroll
      for (int j = 0; j < 3; ++j)
        pqk[i][j] = __builtin_amdgcn_mfma_f32_16x16x32_bf16(qf[i], kf[j], pqk[i][j], 0, 0, 0);
#pragma unroll
    for (int i = 0; i < 3; ++i) {
      pqq[i] = __builtin_amdgcn_mfma_f32_16x16x32_bf16(qf[i], qf[i], pqq[i], 0, 0, 0);
      pkk[i] = __builtin_amdgcn_mfma_f32_16x16x32_bf16(kf[i], kf[i], pkk[i], 0, 0, 0);
    }
  }

#pragma unroll
  for (int i = 0; i < 3; ++i)
#pragma unroll
    for (int j = 0; j < 3; ++j)
#pragma unroll
      for (int r = 0; r < 4; ++r)
        atomicAdd(&attn_raw[i * 16 + lg * 4 + r][j * 16 + lane16], pqk[i][j][r]);
  if (lg == (lane16 >> 2)) {
    const int r = lane16 & 3;
#pragma unroll
    for (int i = 0; i < 3; ++i) {
      atomicAdd(&sqs[0][i * 16 + lane16], pqq[i][r]);
      atomicAdd(&sqs[1][i * 16 + lane16], pkk[i][r]);
    }
  }
  __syncthreads();

  if (tid < 96) {
    const int m = tid / 48, d = tid % 48;
    rn[m][d] = 1.f / fmaxf(sqrtf(sqs[m][d]), 1e-12f);
  }
  __syncthreads();

  const float temp = temperature[h];
  if (tid < 48) {
    const float sr = rn[0][tid] * temp;
    float mx = -1e30f;
    for (int e = 0; e < 48; ++e)
      mx = fmaxf(mx, attn_raw[tid][e] * rn[1][e] * sr);
    float ssum = 0.f;
    for (int e = 0; e < 48; ++e) {
      const float p = __expf(attn_raw[tid][e] * rn[1][e] * sr - mx);
      attn_raw[tid][e] = p; ssum += p;
    }
    const float inv = 1.f / ssum;
    for (int e = 0; e < 48; ++e) attn_bf[tid][e] = f2bf(attn_raw[tid][e] * inv);
    for (int e = 48; e < 64; ++e) attn_bf[tid][e] = 0;
  }
  __syncthreads();

  bf16x8 af2[3][2];
#pragma unroll
  for (int i = 0; i < 3; ++i)
#pragma unroll
    for (int ks = 0; ks < 2; ++ks)
      af2[i][ks] = *(const bf16x8*)&attn_bf[i * 16 + lane16][ks * 32 + lg * 8];

  const bf16x8 zf = {0, 0, 0, 0, 0, 0, 0, 0};
  for (int nf = 0; nf < 16; ++nf) {
    const int n0 = w * 256 + nf * 16;
    const u16* vsrc = qkv + base + 1536 + (size_t)(n0 + lane16) * 2304 + lg * 8;
    bf16x8 vf0 = *(const bf16x8*)vsrc;
    bf16x8 vf1 = (lg < 2) ? *(const bf16x8*)(vsrc + 32) : zf;
#pragma unroll
    for (int i = 0; i < 3; ++i) {
      f32x4 acc = zero;
      acc = __builtin_amdgcn_mfma_f32_16x16x32_bf16(af2[i][0], vf0, acc, 0, 0, 0);
      acc = __builtin_amdgcn_mfma_f32_16x16x32_bf16(af2[i][1], vf1, acc, 0, 0, 0);
      const size_t oo = (size_t)(b * 1024 + n0 + lane16) * 768 + h * 48 + i * 16 + lg * 4;
      ushort4 pack;
      pack.x = f2bf(acc[0]); pack.y = f2bf(acc[1]);
      pack.z = f2bf(acc[2]); pack.w = f2bf(acc[3]);
      *(ushort4*)&aout[oo] = pack;
    }
  }
}

// ---------------------------------------------------------------------------
extern "C" void kernel_launch(void* const* d_in, const int* in_sizes, int n_in,
                              void* d_out, int out_size, void* d_ws, size_t ws_size,
                              hipStream_t stream) {
  const float* x      = (const float*)d_in[0];  // [32768][768]
  const float* w_qkv  = (const float*)d_in[1];  // [2304][768]
  const float* w_proj = (const float*)d_in[2];  // [768][768]
  const float* b_proj = (const float*)d_in[3];  // [768]
  const float* temp   = (const float*)d_in[4];  // [16]
  float* out = (float*)d_out;                   // [32768][768]

  u16* x_bf = (u16*)d_out;                                  // 50.3 MB (dead until GEMM2)
  char* ws = (char*)d_ws;
  u16* qkvb      = (u16*)ws;                                // 151.0 MB
  u16* aoutb     = (u16*)(ws + (size_t)150994944);          // 50.3 MB
  u16* w_qkv_bf  = (u16*)(ws + (size_t)201326592);          // 3.54 MB
  u16* w_proj_bf = (u16*)(ws + (size_t)204865536);          // 1.18 MB

  dim3 blk(256);
  cast_f32_bf16_kernel<<<dim3(32768 * 768 / 1024), blk, 0, stream>>>(
      x, x_bf, 32768 * 768);
  cast_f32_bf16_kernel<<<dim3(2304 * 768 / 1024), blk, 0, stream>>>(
      w_qkv, w_qkv_bf, 2304 * 768);
  cast_f32_bf16_kernel<<<dim3(768 * 768 / 1024), blk, 0, stream>>>(
      w_proj, w_proj_bf, 768 * 768);

  gemm_bt_kernel<0, 0><<<dim3(4608), blk, 0, stream>>>(
      x_bf, w_qkv_bf, qkvb, nullptr, 32768, 2304, 768, 18);
  xca_attn_kernel<<<dim3(512), blk, 0, stream>>>(qkvb, temp, aoutb);
  gemm_bt_kernel<1, 1><<<dim3(1536), blk, 0, stream>>>(
      aoutb, w_proj_bf, out, b_proj, 32768, 768, 768, 6);
}

// Round 8
// 312.974 us; speedup vs baseline: 1.1017x; 1.1017x over previous
//
#include <hip/hip_runtime.h>
#include <hip/hip_bf16.h>

typedef unsigned short u16;
typedef __bf16 bf16x8 __attribute__((ext_vector_type(8)));
typedef u16 u16x8 __attribute__((ext_vector_type(8)));
typedef float f32x4 __attribute__((ext_vector_type(4)));

__device__ __forceinline__ float bf2f(u16 u) {
  union { unsigned u32; float f; } c; c.u32 = ((unsigned)u) << 16; return c.f;
}
__device__ __forceinline__ u16 f2bf(float f) {
  union { float f; unsigned u32; } c; c.f = f;
  unsigned r = c.u32 + 0x7FFFu + ((c.u32 >> 16) & 1u);
  return (u16)(r >> 16);
}

#define GLD16(gp, lp) __builtin_amdgcn_global_load_lds( \
    (const __attribute__((address_space(1))) void*)(gp), \
    (__attribute__((address_space(3))) void*)(lp), 16, 0, 0)

// ---------------------------------------------------------------------------
// fused fp32 -> bf16 cast over three concatenated logical buffers.
// ---------------------------------------------------------------------------
__global__ __launch_bounds__(256)
void cast3_f32_bf16_kernel(const float* __restrict__ in0, u16* __restrict__ out0, int n0,
                           const float* __restrict__ in1, u16* __restrict__ out1, int n1,
                           const float* __restrict__ in2, u16* __restrict__ out2, int n2) {
  int i = (blockIdx.x * 256 + threadIdx.x) * 4;
  const float* in; u16* out;
  if (i < n0)            { in = in0; out = out0; }
  else if (i < n0 + n1)  { in = in1; out = out1; i -= n0; }
  else if (i < n0 + n1 + n2) { in = in2; out = out2; i -= n0 + n1; }
  else return;
  float4 v = *(const float4*)(in + i);
  ushort4 o;
  o.x = f2bf(v.x); o.y = f2bf(v.y); o.z = f2bf(v.z); o.w = f2bf(v.w);
  *(ushort4*)(out + i) = o;
}

// ---------------------------------------------------------------------------
// GEMM (m97 structure, BK=64): C[M,N] = A[M,K] @ B[N,K]^T, bf16 in, fp32
// accum, bf16 or fp32(+bias) out. 128x128 tile, 4 waves, global_load_lds
// width-16. BK=64 is organized as TWO independent [128][32] k-half
// sub-buffers per matrix — staging/read mechanics are exactly the verified
// round-4 pattern, issued twice per iteration. 12 iters for K=768 (half the
// barrier/drain events of BK=32). LDS 32 KB.
// ---------------------------------------------------------------------------
template<int BIAS, int OUTF32>
__global__ __launch_bounds__(256)
void gemm_bt_kernel(const u16* __restrict__ A, const u16* __restrict__ B,
                    void* __restrict__ Cv, const float* __restrict__ bias,
                    int M, int N, int K, int nbn) {
  __shared__ alignas(16) u16 As[2][128][32];   // 16 KB (k-halves)
  __shared__ alignas(16) u16 Bs[2][128][32];   // 16 KB
  const int tid = threadIdx.x;
  const int l = tid & 63, w = tid >> 6;
  const int lane16 = l & 15, lg = l >> 4;
  const int wr = w >> 1, wc = w & 1;
  // bijective XCD swizzle (gridDim.x % 8 == 0 by construction)
  const int cpx = gridDim.x >> 3;
  const int swz = (blockIdx.x & 7) * cpx + (blockIdx.x >> 3);
  const int bm = swz / nbn, bn = swz - bm * nbn;

  const f32x4 zero = {0.f, 0.f, 0.f, 0.f};
  f32x4 acc[4][4];
#pragma unroll
  for (int i = 0; i < 4; ++i)
#pragma unroll
    for (int j = 0; j < 4; ++j) acc[i][j] = zero;

  // round-4 staging geometry per [128][32] sub-tile:
  // chunk c in [0,512): row=c>>2, elem=(c&3)*8; thread owns {tid, tid+256}.
  const int r0 = tid >> 2, e0 = (tid & 3) * 8;
  const u16* Ap0 = A + (size_t)(bm * 128 + r0) * K + e0;
  const u16* Ap1 = A + (size_t)(bm * 128 + r0 + 64) * K + e0;
  const u16* Bp0 = B + (size_t)(bn * 128 + r0) * K + e0;
  const u16* Bp1 = B + (size_t)(bn * 128 + r0 + 64) * K + e0;

  for (int k0 = 0; k0 < K; k0 += 64) {
#pragma unroll
    for (int kk = 0; kk < 2; ++kk) {
      const int ko = k0 + kk * 32;
      GLD16(Ap0 + ko, (char*)&As[kk][0][0] + w * 1024);
      GLD16(Ap1 + ko, (char*)&As[kk][0][0] + 4096 + w * 1024);
      GLD16(Bp0 + ko, (char*)&Bs[kk][0][0] + w * 1024);
      GLD16(Bp1 + ko, (char*)&Bs[kk][0][0] + 4096 + w * 1024);
    }
    __syncthreads();   // vmcnt(0)+lgkmcnt(0) drain before barrier (compiler)

#pragma unroll
    for (int kk = 0; kk < 2; ++kk) {
      bf16x8 af[4], bfr[4];
#pragma unroll
      for (int i = 0; i < 4; ++i)
        af[i] = *(const bf16x8*)&As[kk][wr * 64 + i * 16 + lane16][lg * 8];
#pragma unroll
      for (int j = 0; j < 4; ++j)
        bfr[j] = *(const bf16x8*)&Bs[kk][wc * 64 + j * 16 + lane16][lg * 8];
#pragma unroll
      for (int i = 0; i < 4; ++i)
#pragma unroll
        for (int j = 0; j < 4; ++j)
          acc[i][j] = __builtin_amdgcn_mfma_f32_16x16x32_bf16(af[i], bfr[j], acc[i][j], 0, 0, 0);
    }
    __syncthreads();   // reads done before next iter's staging
  }

  // epilogue: D layout col = lane&15, row = (lane>>4)*4 + reg
  const int row0 = bm * 128 + wr * 64, col0 = bn * 128 + wc * 64;
#pragma unroll
  for (int i = 0; i < 4; ++i) {
#pragma unroll
    for (int j = 0; j < 4; ++j) {
      const int col = col0 + j * 16 + lane16;
      const float badd = BIAS ? bias[col] : 0.f;
      const int rbase = row0 + i * 16 + lg * 4;
#pragma unroll
      for (int r = 0; r < 4; ++r) {
        const float v = acc[i][j][r] + badd;
        if (OUTF32) ((float*)Cv)[(size_t)(rbase + r) * N + col] = v;
        else        ((u16*)Cv)[(size_t)(rbase + r) * N + col] = f2bf(v);
      }
    }
  }
}

// ---------------------------------------------------------------------------
// XCA attention core (unchanged, passing). One block (4 waves) per (b,h).
// ---------------------------------------------------------------------------
__global__ __launch_bounds__(256)
void xca_attn_kernel(const u16* __restrict__ qkv,
                     const float* __restrict__ temperature,
                     u16* __restrict__ aout) {
  const int tid = threadIdx.x;
  const int l = tid & 63, w = tid >> 6;
  const int lane16 = l & 15, lg = l >> 4;
  const int bh = blockIdx.x, b = bh >> 4, h = bh & 15;
  const size_t base = (size_t)b * 1024 * 2304 + (size_t)h * 48;

  __shared__ alignas(16) u16 qt[4][48][32];
  __shared__ alignas(16) u16 kt[4][48][32];
  __shared__ alignas(16) float attn_raw[48][48];
  __shared__ alignas(16) u16 attn_bf[48][64];
  __shared__ float sqs[2][48];
  __shared__ float rn[2][48];

  for (int i = tid; i < 48 * 48; i += 256) ((float*)attn_raw)[i] = 0.f;
  if (tid < 96) ((float*)sqs)[tid] = 0.f;
  __syncthreads();

  const f32x4 zero = {0.f, 0.f, 0.f, 0.f};
  f32x4 pqk[3][3], pqq[3], pkk[3];
#pragma unroll
  for (int i = 0; i < 3; ++i) {
    pqq[i] = zero; pkk[i] = zero;
#pragma unroll
    for (int j = 0; j < 3; ++j) pqk[i][j] = zero;
  }

  for (int s = 0; s < 8; ++s) {
    const int n0 = (s * 4 + w) * 32;
#pragma unroll
    for (int t0 = 0; t0 < 3; ++t0) {
      const int t = t0 * 64 + l;
      const int mat = t >= 96;
      const int tt = t - mat * 96;
      const int d0 = (tt % 12) * 4, nl0 = (tt / 12) * 4;
      const u16* src = qkv + base + (size_t)(n0 + nl0) * 2304 + mat * 768 + d0;
      ushort4 r0 = *(const ushort4*)(src);
      ushort4 r1 = *(const ushort4*)(src + 2304);
      ushort4 r2 = *(const ushort4*)(src + 4608);
      ushort4 r3 = *(const ushort4*)(src + 6912);
      u16 (*dst)[32] = mat ? kt[w] : qt[w];
      ushort4 c;
      c.x = r0.x; c.y = r1.x; c.z = r2.x; c.w = r3.x; *(ushort4*)&dst[d0 + 0][nl0] = c;
      c.x = r0.y; c.y = r1.y; c.z = r2.y; c.w = r3.y; *(ushort4*)&dst[d0 + 1][nl0] = c;
      c.x = r0.z; c.y = r1.z; c.z = r2.z; c.w = r3.z; *(ushort4*)&dst[d0 + 2][nl0] = c;
      c.x = r0.w; c.y = r1.w; c.z = r2.w; c.w = r3.w; *(ushort4*)&dst[d0 + 3][nl0] = c;
    }
    asm volatile("s_waitcnt lgkmcnt(0)" ::: "memory");
    __builtin_amdgcn_sched_barrier(0);

    bf16x8 qf[3], kf[3];
#pragma unroll
    for (int i = 0; i < 3; ++i)
      qf[i] = *(const bf16x8*)&qt[w][i * 16 + lane16][lg * 8];
#pragma unroll
    for (int j = 0; j < 3; ++j)
      kf[j] = *(const bf16x8*)&kt[w][j * 16 + lane16][lg * 8];
#pragma unroll
    for (int i = 0; i < 3; ++i)
#pragma unroll
      for (int j = 0; j < 3; ++j)
        pqk[i][j] = __builtin_amdgcn_mfma_f32_16x16x32_bf16(qf[i], kf[j], pqk[i][j], 0, 0, 0);
#pragma unroll
    for (int i = 0; i < 3; ++i) {
      pqq[i] = __builtin_amdgcn_mfma_f32_16x16x32_bf16(qf[i], qf[i], pqq[i], 0, 0, 0);
      pkk[i] = __builtin_amdgcn_mfma_f32_16x16x32_bf16(kf[i], kf[i], pkk[i], 0, 0, 0);
    }
  }

#pragma unroll
  for (int i = 0; i < 3; ++i)
#pragma unroll
    for (int j = 0; j < 3; ++j)
#pragma unroll
      for (int r = 0; r < 4; ++r)
        atomicAdd(&attn_raw[i * 16 + lg * 4 + r][j * 16 + lane16], pqk[i][j][r]);
  if (lg == (lane16 >> 2)) {
    const int r = lane16 & 3;
#pragma unroll
    for (int i = 0; i < 3; ++i) {
      atomicAdd(&sqs[0][i * 16 + lane16], pqq[i][r]);
      atomicAdd(&sqs[1][i * 16 + lane16], pkk[i][r]);
    }
  }
  __syncthreads();

  if (tid < 96) {
    const int m = tid / 48, d = tid % 48;
    rn[m][d] = 1.f / fmaxf(sqrtf(sqs[m][d]), 1e-12f);
  }
  __syncthreads();

  const float temp = temperature[h];
  if (tid < 48) {
    const float sr = rn[0][tid] * temp;
    float mx = -1e30f;
    for (int e = 0; e < 48; ++e)
      mx = fmaxf(mx, attn_raw[tid][e] * rn[1][e] * sr);
    float ssum = 0.f;
    for (int e = 0; e < 48; ++e) {
      const float p = __expf(attn_raw[tid][e] * rn[1][e] * sr - mx);
      attn_raw[tid][e] = p; ssum += p;
    }
    const float inv = 1.f / ssum;
    for (int e = 0; e < 48; ++e) attn_bf[tid][e] = f2bf(attn_raw[tid][e] * inv);
    for (int e = 48; e < 64; ++e) attn_bf[tid][e] = 0;
  }
  __syncthreads();

  bf16x8 af2[3][2];
#pragma unroll
  for (int i = 0; i < 3; ++i)
#pragma unroll
    for (int ks = 0; ks < 2; ++ks)
      af2[i][ks] = *(const bf16x8*)&attn_bf[i * 16 + lane16][ks * 32 + lg * 8];

  const bf16x8 zf = {0, 0, 0, 0, 0, 0, 0, 0};
  for (int nf = 0; nf < 16; ++nf) {
    const int n0 = w * 256 + nf * 16;
    const u16* vsrc = qkv + base + 1536 + (size_t)(n0 + lane16) * 2304 + lg * 8;
    bf16x8 vf0 = *(const bf16x8*)vsrc;
    bf16x8 vf1 = (lg < 2) ? *(const bf16x8*)(vsrc + 32) : zf;
#pragma unroll
    for (int i = 0; i < 3; ++i) {
      f32x4 acc = zero;
      acc = __builtin_amdgcn_mfma_f32_16x16x32_bf16(af2[i][0], vf0, acc, 0, 0, 0);
      acc = __builtin_amdgcn_mfma_f32_16x16x32_bf16(af2[i][1], vf1, acc, 0, 0, 0);
      const size_t oo = (size_t)(b * 1024 + n0 + lane16) * 768 + h * 48 + i * 16 + lg * 4;
      ushort4 pack;
      pack.x = f2bf(acc[0]); pack.y = f2bf(acc[1]);
      pack.z = f2bf(acc[2]); pack.w = f2bf(acc[3]);
      *(ushort4*)&aout[oo] = pack;
    }
  }
}

// ---------------------------------------------------------------------------
extern "C" void kernel_launch(void* const* d_in, const int* in_sizes, int n_in,
                              void* d_out, int out_size, void* d_ws, size_t ws_size,
                              hipStream_t stream) {
  const float* x      = (const float*)d_in[0];  // [32768][768]
  const float* w_qkv  = (const float*)d_in[1];  // [2304][768]
  const float* w_proj = (const float*)d_in[2];  // [768][768]
  const float* b_proj = (const float*)d_in[3];  // [768]
  const float* temp   = (const float*)d_in[4];  // [16]
  float* out = (float*)d_out;                   // [32768][768]

  u16* x_bf = (u16*)d_out;                                  // dead until GEMM2
  char* ws = (char*)d_ws;
  u16* qkvb      = (u16*)ws;                                // 151.0 MB
  u16* aoutb     = (u16*)(ws + (size_t)150994944);          // 50.3 MB
  u16* w_qkv_bf  = (u16*)(ws + (size_t)201326592);          // 3.54 MB
  u16* w_proj_bf = (u16*)(ws + (size_t)204865536);          // 1.18 MB

  dim3 blk(256);
  const int n0 = 32768 * 768, n1 = 2304 * 768, n2 = 768 * 768;
  cast3_f32_bf16_kernel<<<dim3((n0 + n1 + n2) / 1024), blk, 0, stream>>>(
      x, x_bf, n0, w_qkv, w_qkv_bf, n1, w_proj, w_proj_bf, n2);

  // qkv = x @ w_qkv^T : 256x18 -> 4608 blocks (div by 8), BK=64
  gemm_bt_kernel<0, 0><<<dim3(4608), blk, 0, stream>>>(
      x_bf, w_qkv_bf, qkvb, nullptr, 32768, 2304, 768, 18);
  // attention core -> aoutb [B,N,C] bf16
  xca_attn_kernel<<<dim3(512), blk, 0, stream>>>(qkvb, temp, aoutb);
  // out = aoutb @ w_proj^T + b_proj : 256x6 -> 1536 blocks
  gemm_bt_kernel<1, 1><<<dim3(1536), blk, 0, stream>>>(
      aoutb, w_proj_bf, out, b_proj, 32768, 768, 768, 6);
}

// Round 9
// 304.503 us; speedup vs baseline: 1.1323x; 1.0278x over previous
//
#include <hip/hip_runtime.h>
#include <hip/hip_bf16.h>

typedef unsigned short u16;
typedef __bf16 bf16x8 __attribute__((ext_vector_type(8)));
typedef u16 u16x8 __attribute__((ext_vector_type(8)));
typedef float f32x4 __attribute__((ext_vector_type(4)));

__device__ __forceinline__ float bf2f(u16 u) {
  union { unsigned u32; float f; } c; c.u32 = ((unsigned)u) << 16; return c.f;
}
__device__ __forceinline__ u16 f2bf(float f) {
  union { float f; unsigned u32; } c; c.f = f;
  unsigned r = c.u32 + 0x7FFFu + ((c.u32 >> 16) & 1u);
  return (u16)(r >> 16);
}

#define GLD16(gp, lp) __builtin_amdgcn_global_load_lds( \
    (const __attribute__((address_space(1))) void*)(gp), \
    (__attribute__((address_space(3))) void*)(lp), 16, 0, 0)

// ---------------------------------------------------------------------------
// fused fp32 -> bf16 cast over three concatenated logical buffers.
// ---------------------------------------------------------------------------
__global__ __launch_bounds__(256)
void cast3_f32_bf16_kernel(const float* __restrict__ in0, u16* __restrict__ out0, int n0,
                           const float* __restrict__ in1, u16* __restrict__ out1, int n1,
                           const float* __restrict__ in2, u16* __restrict__ out2, int n2) {
  int i = (blockIdx.x * 256 + threadIdx.x) * 4;
  const float* in; u16* out;
  if (i < n0)            { in = in0; out = out0; }
  else if (i < n0 + n1)  { in = in1; out = out1; i -= n0; }
  else if (i < n0 + n1 + n2) { in = in2; out = out2; i -= n0 + n1; }
  else return;
  float4 v = *(const float4*)(in + i);
  ushort4 o;
  o.x = f2bf(v.x); o.y = f2bf(v.y); o.z = f2bf(v.z); o.w = f2bf(v.w);
  *(ushort4*)(out + i) = o;
}

// ===========================================================================
// 8-phase 256x256 GEMM (T1+T2+T3+T4+T5), C = A[M,K] @ B[N,K]^T, bf16 in.
// FIXED stage slots vs rounds 6/7: A regions (0,1) are read by their owner
// waves (region = wm) in BOTH ph1 and ph3 of each buf's half-iteration, so
// they may only be staged in ph4 (after ph3's closing barrier). B regions
// (2,3) are read only in ph1 -> staged in ph2/ph3. Rounds 6/7 staged region
// 0 at ph2, clobbering the A data wm=0 waves re-read at ph3 (deterministic
// half-wave corruption, absmax 1.195 both rounds).
// vmcnt: 8 loads per half-iter (2+2+4); VMC8 at ph4/ph8 drains exactly the
// prior half-iter's 8 -> that buf's tile is ready one phase before use.
// ===========================================================================
template<int BIAS, int OUTF32>
__global__ __launch_bounds__(512, 2)
void gemm8p_kernel(const u16* __restrict__ A, const u16* __restrict__ B,
                   void* __restrict__ Cv, const float* __restrict__ bias,
                   int M, int N, int K, int nbn, int niter) {
  __shared__ alignas(16) u16 lds[2][4][128][64];   // 131072 B
  const int tid = threadIdx.x;
  const int l = tid & 63, w = tid >> 6;
  const int lane16 = l & 15, lg = l >> 4;
  const int wm = w >> 2, wn = w & 3;
  const int lsub = l >> 3;
  const int colsw = ((l & 7) ^ lsub) * 8;      // inverse-swizzled source col
  const int swzrd = (lane16 & 7) << 4;         // read-side XOR

  const int cpx = gridDim.x >> 3;
  const int swz = (blockIdx.x & 7) * cpx + (blockIdx.x >> 3);
  const int bm = swz / nbn, bn = swz - bm * nbn;

  const u16* rbase[4] = {
    A + (size_t)(bm * 256) * K,        A + (size_t)(bm * 256 + 128) * K,
    B + (size_t)(bn * 256) * K,        B + (size_t)(bn * 256 + 128) * K };

  const f32x4 zero = {0.f, 0.f, 0.f, 0.f};
  f32x4 acc[8][4];
#pragma unroll
  for (int i = 0; i < 8; ++i)
#pragma unroll
    for (int j = 0; j < 4; ++j) acc[i][j] = zero;

  bf16x8 af[4][2], bf[2][2][2];

#define STG(D, REG, C, T) \
  GLD16(rbase[REG] + (size_t)((C) * 64 + w * 8 + lsub) * K + colsw + (T) * 64, \
        (char*)&lds[D][REG][0][0] + (C) * 8192 + w * 1024)

#define RD_A(D, MH) do { \
  _Pragma("unroll") for (int m = 0; m < 4; ++m) \
  _Pragma("unroll") for (int kh = 0; kh < 2; ++kh) \
    af[m][kh] = *(const bf16x8*)((const char*)&lds[D][wm][0][0] \
        + ((MH) * 64 + m * 16 + lane16) * 128 + ((kh * 64 + lg * 16) ^ swzrd)); \
  } while (0)

#define RD_B(D) do { \
  _Pragma("unroll") for (int nh = 0; nh < 2; ++nh) \
  _Pragma("unroll") for (int n = 0; n < 2; ++n) \
  _Pragma("unroll") for (int kh = 0; kh < 2; ++kh) \
    bf[nh][n][kh] = *(const bf16x8*)((const char*)&lds[D][2 + (wn >> 1)][0][0] \
        + ((wn & 1) * 64 + (nh * 2 + n) * 16 + lane16) * 128 \
        + ((kh * 64 + lg * 16) ^ swzrd)); \
  } while (0)

#define QUAD(MH, NH) do { \
  __builtin_amdgcn_s_setprio(1); \
  _Pragma("unroll") for (int m = 0; m < 4; ++m) \
  _Pragma("unroll") for (int n = 0; n < 2; ++n) \
  _Pragma("unroll") for (int kh = 0; kh < 2; ++kh) \
    acc[(MH) * 4 + m][(NH) * 2 + n] = __builtin_amdgcn_mfma_f32_16x16x32_bf16( \
        af[m][kh], bf[NH][n][kh], acc[(MH) * 4 + m][(NH) * 2 + n], 0, 0, 0); \
  __builtin_amdgcn_s_setprio(0); \
  } while (0)

#define BARR  do { asm volatile("s_barrier" ::: "memory"); \
                   __builtin_amdgcn_sched_barrier(0); } while (0)
#define LGKM0 asm volatile("s_waitcnt lgkmcnt(0)" ::: "memory")
#define SB0   __builtin_amdgcn_sched_barrier(0)
#define VMC8  asm volatile("s_waitcnt vmcnt(8)" ::: "memory")
#define VMC0  asm volatile("s_waitcnt vmcnt(0)" ::: "memory")

  // prologue: tiles 0 (buf0) and 1 (buf1) fully staged, full drain
#pragma unroll
  for (int reg = 0; reg < 4; ++reg) {
    STG(0, reg, 0, 0); STG(0, reg, 1, 0);
    STG(1, reg, 0, 1); STG(1, reg, 1, 1);
  }
  VMC0; BARR;

  for (int it = 0; it < niter; ++it) {
    const int t = 2 * it;
    const bool pf = (it < niter - 1);
    // ---- ph1: (mh0,nh0) buf0; reads A(region wm) + B(regions 2,3) ----
    RD_A(0, 0); RD_B(0);
    BARR; LGKM0; SB0;
    QUAD(0, 0);
    BARR;
    // ---- ph2: (mh0,nh1); stage t+2: B0 (region 2; B last read ph1) ----
    if (pf) { STG(0, 2, 0, t + 2); STG(0, 2, 1, t + 2); }
    BARR; LGKM0; SB0;
    QUAD(0, 1);
    BARR;
    // ---- ph3: (mh1,*): reads A(region wm) again; stage t+2: B1 (region 3) ----
    RD_A(0, 1);
    if (pf) { STG(0, 3, 0, t + 2); STG(0, 3, 1, t + 2); }
    BARR; LGKM0; SB0;
    QUAD(1, 1);
    BARR;
    // ---- ph4: (mh1,nh0); stage t+2: A0+A1 (regions 0,1; A last read ph3) ----
    if (pf) { STG(0, 0, 0, t + 2); STG(0, 0, 1, t + 2);
              STG(0, 1, 0, t + 2); STG(0, 1, 1, t + 2); }
    BARR; LGKM0; SB0;
    QUAD(1, 0);
    if (pf) { VMC8; } else { VMC0; }
    BARR;
    // ---- ph5: (mh0,nh0) buf1 ----
    RD_A(1, 0); RD_B(1);
    BARR; LGKM0; SB0;
    QUAD(0, 0);
    BARR;
    // ---- ph6: (mh0,nh1); stage t+3: B0' ----
    if (pf) { STG(1, 2, 0, t + 3); STG(1, 2, 1, t + 3); }
    BARR; LGKM0; SB0;
    QUAD(0, 1);
    BARR;
    // ---- ph7: (mh1,*); stage t+3: B1' ----
    RD_A(1, 1);
    if (pf) { STG(1, 3, 0, t + 3); STG(1, 3, 1, t + 3); }
    BARR; LGKM0; SB0;
    QUAD(1, 1);
    BARR;
    // ---- ph8: (mh1,nh0); stage t+3: A0'+A1' ----
    if (pf) { STG(1, 0, 0, t + 3); STG(1, 0, 1, t + 3);
              STG(1, 1, 0, t + 3); STG(1, 1, 1, t + 3); }
    BARR; LGKM0; SB0;
    QUAD(1, 0);
    if (pf) { VMC8; } else { VMC0; }
    BARR;
  }

#undef STG
#undef RD_A
#undef RD_B
#undef QUAD
#undef BARR
#undef LGKM0
#undef SB0
#undef VMC8
#undef VMC0

  // epilogue: D layout col = lane16, row = lg*4 + r
  const int row00 = bm * 256 + wm * 128, col00 = bn * 256 + wn * 64;
#pragma unroll
  for (int mf = 0; mf < 8; ++mf) {
#pragma unroll
    for (int nf = 0; nf < 4; ++nf) {
      const int col = col00 + nf * 16 + lane16;
      const float badd = BIAS ? bias[col] : 0.f;
      const int rb = row00 + mf * 16 + lg * 4;
#pragma unroll
      for (int r = 0; r < 4; ++r) {
        const float v = acc[mf][nf][r] + badd;
        if (OUTF32) ((float*)Cv)[(size_t)(rb + r) * N + col] = v;
        else        ((u16*)Cv)[(size_t)(rb + r) * N + col] = f2bf(v);
      }
    }
  }
}

// ---------------------------------------------------------------------------
// BK=64 128x128 GEMM (round-8, known good) — projection GEMM.
// ---------------------------------------------------------------------------
template<int BIAS, int OUTF32>
__global__ __launch_bounds__(256)
void gemm_bt_kernel(const u16* __restrict__ A, const u16* __restrict__ B,
                    void* __restrict__ Cv, const float* __restrict__ bias,
                    int M, int N, int K, int nbn) {
  __shared__ alignas(16) u16 As[2][128][32];
  __shared__ alignas(16) u16 Bs[2][128][32];
  const int tid = threadIdx.x;
  const int l = tid & 63, w = tid >> 6;
  const int lane16 = l & 15, lg = l >> 4;
  const int wr = w >> 1, wc = w & 1;
  const int cpx = gridDim.x >> 3;
  const int swz = (blockIdx.x & 7) * cpx + (blockIdx.x >> 3);
  const int bm = swz / nbn, bn = swz - bm * nbn;

  const f32x4 zero = {0.f, 0.f, 0.f, 0.f};
  f32x4 acc[4][4];
#pragma unroll
  for (int i = 0; i < 4; ++i)
#pragma unroll
    for (int j = 0; j < 4; ++j) acc[i][j] = zero;

  const int r0 = tid >> 2, e0 = (tid & 3) * 8;
  const u16* Ap0 = A + (size_t)(bm * 128 + r0) * K + e0;
  const u16* Ap1 = A + (size_t)(bm * 128 + r0 + 64) * K + e0;
  const u16* Bp0 = B + (size_t)(bn * 128 + r0) * K + e0;
  const u16* Bp1 = B + (size_t)(bn * 128 + r0 + 64) * K + e0;

  for (int k0 = 0; k0 < K; k0 += 64) {
#pragma unroll
    for (int kk = 0; kk < 2; ++kk) {
      const int ko = k0 + kk * 32;
      GLD16(Ap0 + ko, (char*)&As[kk][0][0] + w * 1024);
      GLD16(Ap1 + ko, (char*)&As[kk][0][0] + 4096 + w * 1024);
      GLD16(Bp0 + ko, (char*)&Bs[kk][0][0] + w * 1024);
      GLD16(Bp1 + ko, (char*)&Bs[kk][0][0] + 4096 + w * 1024);
    }
    __syncthreads();

#pragma unroll
    for (int kk = 0; kk < 2; ++kk) {
      bf16x8 af[4], bfr[4];
#pragma unroll
      for (int i = 0; i < 4; ++i)
        af[i] = *(const bf16x8*)&As[kk][wr * 64 + i * 16 + lane16][lg * 8];
#pragma unroll
      for (int j = 0; j < 4; ++j)
        bfr[j] = *(const bf16x8*)&Bs[kk][wc * 64 + j * 16 + lane16][lg * 8];
#pragma unroll
      for (int i = 0; i < 4; ++i)
#pragma unroll
        for (int j = 0; j < 4; ++j)
          acc[i][j] = __builtin_amdgcn_mfma_f32_16x16x32_bf16(af[i], bfr[j], acc[i][j], 0, 0, 0);
    }
    __syncthreads();
  }

  const int row0 = bm * 128 + wr * 64, col0 = bn * 128 + wc * 64;
#pragma unroll
  for (int i = 0; i < 4; ++i) {
#pragma unroll
    for (int j = 0; j < 4; ++j) {
      const int col = col0 + j * 16 + lane16;
      const float badd = BIAS ? bias[col] : 0.f;
      const int rbase = row0 + i * 16 + lg * 4;
#pragma unroll
      for (int r = 0; r < 4; ++r) {
        const float v = acc[i][j][r] + badd;
        if (OUTF32) ((float*)Cv)[(size_t)(rbase + r) * N + col] = v;
        else        ((u16*)Cv)[(size_t)(rbase + r) * N + col] = f2bf(v);
      }
    }
  }
}

// ---------------------------------------------------------------------------
// XCA attention core (unchanged, passing). One block (4 waves) per (b,h).
// ---------------------------------------------------------------------------
__global__ __launch_bounds__(256)
void xca_attn_kernel(const u16* __restrict__ qkv,
                     const float* __restrict__ temperature,
                     u16* __restrict__ aout) {
  const int tid = threadIdx.x;
  const int l = tid & 63, w = tid >> 6;
  const int lane16 = l & 15, lg = l >> 4;
  const int bh = blockIdx.x, b = bh >> 4, h = bh & 15;
  const size_t base = (size_t)b * 1024 * 2304 + (size_t)h * 48;

  __shared__ alignas(16) u16 qt[4][48][32];
  __shared__ alignas(16) u16 kt[4][48][32];
  __shared__ alignas(16) float attn_raw[48][48];
  __shared__ alignas(16) u16 attn_bf[48][64];
  __shared__ float sqs[2][48];
  __shared__ float rn[2][48];

  for (int i = tid; i < 48 * 48; i += 256) ((float*)attn_raw)[i] = 0.f;
  if (tid < 96) ((float*)sqs)[tid] = 0.f;
  __syncthreads();

  const f32x4 zero = {0.f, 0.f, 0.f, 0.f};
  f32x4 pqk[3][3], pqq[3], pkk[3];
#pragma unroll
  for (int i = 0; i < 3; ++i) {
    pqq[i] = zero; pkk[i] = zero;
#pragma unroll
    for (int j = 0; j < 3; ++j) pqk[i][j] = zero;
  }

  for (int s = 0; s < 8; ++s) {
    const int n0 = (s * 4 + w) * 32;
#pragma unroll
    for (int t0 = 0; t0 < 3; ++t0) {
      const int t = t0 * 64 + l;
      const int mat = t >= 96;
      const int tt = t - mat * 96;
      const int d0 = (tt % 12) * 4, nl0 = (tt / 12) * 4;
      const u16* src = qkv + base + (size_t)(n0 + nl0) * 2304 + mat * 768 + d0;
      ushort4 r0 = *(const ushort4*)(src);
      ushort4 r1 = *(const ushort4*)(src + 2304);
      ushort4 r2 = *(const ushort4*)(src + 4608);
      ushort4 r3 = *(const ushort4*)(src + 6912);
      u16 (*dst)[32] = mat ? kt[w] : qt[w];
      ushort4 c;
      c.x = r0.x; c.y = r1.x; c.z = r2.x; c.w = r3.x; *(ushort4*)&dst[d0 + 0][nl0] = c;
      c.x = r0.y; c.y = r1.y; c.z = r2.y; c.w = r3.y; *(ushort4*)&dst[d0 + 1][nl0] = c;
      c.x = r0.z; c.y = r1.z; c.z = r2.z; c.w = r3.z; *(ushort4*)&dst[d0 + 2][nl0] = c;
      c.x = r0.w; c.y = r1.w; c.z = r2.w; c.w = r3.w; *(ushort4*)&dst[d0 + 3][nl0] = c;
    }
    asm volatile("s_waitcnt lgkmcnt(0)" ::: "memory");
    __builtin_amdgcn_sched_barrier(0);

    bf16x8 qf[3], kf[3];
#pragma unroll
    for (int i = 0; i < 3; ++i)
      qf[i] = *(const bf16x8*)&qt[w][i * 16 + lane16][lg * 8];
#pragma unroll
    for (int j = 0; j < 3; ++j)
      kf[j] = *(const bf16x8*)&kt[w][j * 16 + lane16][lg * 8];
#pragma unroll
    for (int i = 0; i < 3; ++i)
#pragma unroll
      for (int j = 0; j < 3; ++j)
        pqk[i][j] = __builtin_amdgcn_mfma_f32_16x16x32_bf16(qf[i], kf[j], pqk[i][j], 0, 0, 0);
#pragma unroll
    for (int i = 0; i < 3; ++i) {
      pqq[i] = __builtin_amdgcn_mfma_f32_16x16x32_bf16(qf[i], qf[i], pqq[i], 0, 0, 0);
      pkk[i] = __builtin_amdgcn_mfma_f32_16x16x32_bf16(kf[i], kf[i], pkk[i], 0, 0, 0);
    }
  }

#pragma unroll
  for (int i = 0; i < 3; ++i)
#pragma unroll
    for (int j = 0; j < 3; ++j)
#pragma unroll
      for (int r = 0; r < 4; ++r)
        atomicAdd(&attn_raw[i * 16 + lg * 4 + r][j * 16 + lane16], pqk[i][j][r]);
  if (lg == (lane16 >> 2)) {
    const int r = lane16 & 3;
#pragma unroll
    for (int i = 0; i < 3; ++i) {
      atomicAdd(&sqs[0][i * 16 + lane16], pqq[i][r]);
      atomicAdd(&sqs[1][i * 16 + lane16], pkk[i][r]);
    }
  }
  __syncthreads();

  if (tid < 96) {
    const int m = tid / 48, d = tid % 48;
    rn[m][d] = 1.f / fmaxf(sqrtf(sqs[m][d]), 1e-12f);
  }
  __syncthreads();

  const float temp = temperature[h];
  if (tid < 48) {
    const float sr = rn[0][tid] * temp;
    float mx = -1e30f;
    for (int e = 0; e < 48; ++e)
      mx = fmaxf(mx, attn_raw[tid][e] * rn[1][e] * sr);
    float ssum = 0.f;
    for (int e = 0; e < 48; ++e) {
      const float p = __expf(attn_raw[tid][e] * rn[1][e] * sr - mx);
      attn_raw[tid][e] = p; ssum += p;
    }
    const float inv = 1.f / ssum;
    for (int e = 0; e < 48; ++e) attn_bf[tid][e] = f2bf(attn_raw[tid][e] * inv);
    for (int e = 48; e < 64; ++e) attn_bf[tid][e] = 0;
  }
  __syncthreads();

  bf16x8 af2[3][2];
#pragma unroll
  for (int i = 0; i < 3; ++i)
#pragma unroll
    for (int ks = 0; ks < 2; ++ks)
      af2[i][ks] = *(const bf16x8*)&attn_bf[i * 16 + lane16][ks * 32 + lg * 8];

  const bf16x8 zf = {0, 0, 0, 0, 0, 0, 0, 0};
  for (int nf = 0; nf < 16; ++nf) {
    const int n0 = w * 256 + nf * 16;
    const u16* vsrc = qkv + base + 1536 + (size_t)(n0 + lane16) * 2304 + lg * 8;
    bf16x8 vf0 = *(const bf16x8*)vsrc;
    bf16x8 vf1 = (lg < 2) ? *(const bf16x8*)(vsrc + 32) : zf;
#pragma unroll
    for (int i = 0; i < 3; ++i) {
      f32x4 acc = zero;
      acc = __builtin_amdgcn_mfma_f32_16x16x32_bf16(af2[i][0], vf0, acc, 0, 0, 0);
      acc = __builtin_amdgcn_mfma_f32_16x16x32_bf16(af2[i][1], vf1, acc, 0, 0, 0);
      const size_t oo = (size_t)(b * 1024 + n0 + lane16) * 768 + h * 48 + i * 16 + lg * 4;
      ushort4 pack;
      pack.x = f2bf(acc[0]); pack.y = f2bf(acc[1]);
      pack.z = f2bf(acc[2]); pack.w = f2bf(acc[3]);
      *(ushort4*)&aout[oo] = pack;
    }
  }
}

// ---------------------------------------------------------------------------
extern "C" void kernel_launch(void* const* d_in, const int* in_sizes, int n_in,
                              void* d_out, int out_size, void* d_ws, size_t ws_size,
                              hipStream_t stream) {
  const float* x      = (const float*)d_in[0];  // [32768][768]
  const float* w_qkv  = (const float*)d_in[1];  // [2304][768]
  const float* w_proj = (const float*)d_in[2];  // [768][768]
  const float* b_proj = (const float*)d_in[3];  // [768]
  const float* temp   = (const float*)d_in[4];  // [16]
  float* out = (float*)d_out;                   // [32768][768]

  u16* x_bf = (u16*)d_out;                                  // dead until GEMM2
  char* ws = (char*)d_ws;
  u16* qkvb      = (u16*)ws;                                // 151.0 MB
  u16* aoutb     = (u16*)(ws + (size_t)150994944);          // 50.3 MB
  u16* w_qkv_bf  = (u16*)(ws + (size_t)201326592);          // 3.54 MB
  u16* w_proj_bf = (u16*)(ws + (size_t)204865536);          // 1.18 MB

  dim3 blk(256);
  const int n0 = 32768 * 768, n1 = 2304 * 768, n2 = 768 * 768;
  cast3_f32_bf16_kernel<<<dim3((n0 + n1 + n2) / 1024), blk, 0, stream>>>(
      x, x_bf, n0, w_qkv, w_qkv_bf, n1, w_proj, w_proj_bf, n2);

  // qkv = x @ w_qkv^T : 8-phase 256^2; grid 128x9 = 1152 (div 8); 6 iters.
  gemm8p_kernel<0, 0><<<dim3(1152), dim3(512), 0, stream>>>(
      x_bf, w_qkv_bf, qkvb, nullptr, 32768, 2304, 768, 9, 6);
  // attention core -> aoutb [B,N,C] bf16
  xca_attn_kernel<<<dim3(512), blk, 0, stream>>>(qkvb, temp, aoutb);
  // out = aoutb @ w_proj^T + b_proj : BK=64 128^2, 256x6 -> 1536 blocks
  gemm_bt_kernel<1, 1><<<dim3(1536), blk, 0, stream>>>(
      aoutb, w_proj_bf, out, b_proj, 32768, 768, 768, 6);
}

// Round 10
// 301.746 us; speedup vs baseline: 1.1427x; 1.0091x over previous
//
#include <hip/hip_runtime.h>
#include <hip/hip_bf16.h>

typedef unsigned short u16;
typedef __bf16 bf16x8 __attribute__((ext_vector_type(8)));
typedef u16 u16x8 __attribute__((ext_vector_type(8)));
typedef float f32x4 __attribute__((ext_vector_type(4)));

__device__ __forceinline__ float bf2f(u16 u) {
  union { unsigned u32; float f; } c; c.u32 = ((unsigned)u) << 16; return c.f;
}
__device__ __forceinline__ u16 f2bf(float f) {
  union { float f; unsigned u32; } c; c.f = f;
  unsigned r = c.u32 + 0x7FFFu + ((c.u32 >> 16) & 1u);
  return (u16)(r >> 16);
}

#define GLD16(gp, lp) __builtin_amdgcn_global_load_lds( \
    (const __attribute__((address_space(1))) void*)(gp), \
    (__attribute__((address_space(3))) void*)(lp), 16, 0, 0)

// ---------------------------------------------------------------------------
// fused fp32 -> bf16 cast over three concatenated logical buffers.
// ---------------------------------------------------------------------------
__global__ __launch_bounds__(256)
void cast3_f32_bf16_kernel(const float* __restrict__ in0, u16* __restrict__ out0, int n0,
                           const float* __restrict__ in1, u16* __restrict__ out1, int n1,
                           const float* __restrict__ in2, u16* __restrict__ out2, int n2) {
  int i = (blockIdx.x * 256 + threadIdx.x) * 4;
  const float* in; u16* out;
  if (i < n0)            { in = in0; out = out0; }
  else if (i < n0 + n1)  { in = in1; out = out1; i -= n0; }
  else if (i < n0 + n1 + n2) { in = in2; out = out2; i -= n0 + n1; }
  else return;
  float4 v = *(const float4*)(in + i);
  ushort4 o;
  o.x = f2bf(v.x); o.y = f2bf(v.y); o.z = f2bf(v.z); o.w = f2bf(v.w);
  *(ushort4*)(out + i) = o;
}

// ===========================================================================
// 8-phase 256x256 GEMM (round-9 schedule, passing, bank-conflict-free).
// EPI=0: plain row-major C (bf16/fp32+bias).  EPI=1 (qkv split): N=2304,
// bn 0-2 -> qT[b][h][48][1024] transposed, bn 3-5 -> kT same, bn 6-8 ->
// v[b*1024+n][768] n-major. Transposed writes: each lane's 4 acc values are
// consecutive n -> contiguous ushort4; adjacent mf/lg fragments fill each
// 64B line (L2 merges).
// ===========================================================================
template<int BIAS, int OUTF32, int EPI>
__global__ __launch_bounds__(512, 2)
void gemm8p_kernel(const u16* __restrict__ A, const u16* __restrict__ B,
                   void* __restrict__ Cv, const float* __restrict__ bias,
                   u16* __restrict__ qT, u16* __restrict__ kT,
                   u16* __restrict__ vb,
                   int M, int N, int K, int nbn, int niter) {
  __shared__ alignas(16) u16 lds[2][4][128][64];   // 131072 B
  const int tid = threadIdx.x;
  const int l = tid & 63, w = tid >> 6;
  const int lane16 = l & 15, lg = l >> 4;
  const int wm = w >> 2, wn = w & 3;
  const int lsub = l >> 3;
  const int colsw = ((l & 7) ^ lsub) * 8;      // inverse-swizzled source col
  const int swzrd = (lane16 & 7) << 4;         // read-side XOR

  const int cpx = gridDim.x >> 3;
  const int swz = (blockIdx.x & 7) * cpx + (blockIdx.x >> 3);
  const int bm = swz / nbn, bn = swz - bm * nbn;

  const u16* rbase[4] = {
    A + (size_t)(bm * 256) * K,        A + (size_t)(bm * 256 + 128) * K,
    B + (size_t)(bn * 256) * K,        B + (size_t)(bn * 256 + 128) * K };

  const f32x4 zero = {0.f, 0.f, 0.f, 0.f};
  f32x4 acc[8][4];
#pragma unroll
  for (int i = 0; i < 8; ++i)
#pragma unroll
    for (int j = 0; j < 4; ++j) acc[i][j] = zero;

  bf16x8 af[4][2], bf[2][2][2];

#define STG(D, REG, C, T) \
  GLD16(rbase[REG] + (size_t)((C) * 64 + w * 8 + lsub) * K + colsw + (T) * 64, \
        (char*)&lds[D][REG][0][0] + (C) * 8192 + w * 1024)

#define RD_A(D, MH) do { \
  _Pragma("unroll") for (int m = 0; m < 4; ++m) \
  _Pragma("unroll") for (int kh = 0; kh < 2; ++kh) \
    af[m][kh] = *(const bf16x8*)((const char*)&lds[D][wm][0][0] \
        + ((MH) * 64 + m * 16 + lane16) * 128 + ((kh * 64 + lg * 16) ^ swzrd)); \
  } while (0)

#define RD_B(D) do { \
  _Pragma("unroll") for (int nh = 0; nh < 2; ++nh) \
  _Pragma("unroll") for (int n = 0; n < 2; ++n) \
  _Pragma("unroll") for (int kh = 0; kh < 2; ++kh) \
    bf[nh][n][kh] = *(const bf16x8*)((const char*)&lds[D][2 + (wn >> 1)][0][0] \
        + ((wn & 1) * 64 + (nh * 2 + n) * 16 + lane16) * 128 \
        + ((kh * 64 + lg * 16) ^ swzrd)); \
  } while (0)

#define QUAD(MH, NH) do { \
  __builtin_amdgcn_s_setprio(1); \
  _Pragma("unroll") for (int m = 0; m < 4; ++m) \
  _Pragma("unroll") for (int n = 0; n < 2; ++n) \
  _Pragma("unroll") for (int kh = 0; kh < 2; ++kh) \
    acc[(MH) * 4 + m][(NH) * 2 + n] = __builtin_amdgcn_mfma_f32_16x16x32_bf16( \
        af[m][kh], bf[NH][n][kh], acc[(MH) * 4 + m][(NH) * 2 + n], 0, 0, 0); \
  __builtin_amdgcn_s_setprio(0); \
  } while (0)

#define BARR  do { asm volatile("s_barrier" ::: "memory"); \
                   __builtin_amdgcn_sched_barrier(0); } while (0)
#define LGKM0 asm volatile("s_waitcnt lgkmcnt(0)" ::: "memory")
#define SB0   __builtin_amdgcn_sched_barrier(0)
#define VMC8  asm volatile("s_waitcnt vmcnt(8)" ::: "memory")
#define VMC0  asm volatile("s_waitcnt vmcnt(0)" ::: "memory")

  // prologue: tiles 0 (buf0) and 1 (buf1) fully staged, full drain
#pragma unroll
  for (int reg = 0; reg < 4; ++reg) {
    STG(0, reg, 0, 0); STG(0, reg, 1, 0);
    STG(1, reg, 0, 1); STG(1, reg, 1, 1);
  }
  VMC0; BARR;

  for (int it = 0; it < niter; ++it) {
    const int t = 2 * it;
    const bool pf = (it < niter - 1);
    // ph1: (mh0,nh0) buf0
    RD_A(0, 0); RD_B(0);
    BARR; LGKM0; SB0;
    QUAD(0, 0);
    BARR;
    // ph2: stage t+2: B0 (region 2)
    if (pf) { STG(0, 2, 0, t + 2); STG(0, 2, 1, t + 2); }
    BARR; LGKM0; SB0;
    QUAD(0, 1);
    BARR;
    // ph3: reads A again; stage t+2: B1 (region 3)
    RD_A(0, 1);
    if (pf) { STG(0, 3, 0, t + 2); STG(0, 3, 1, t + 2); }
    BARR; LGKM0; SB0;
    QUAD(1, 1);
    BARR;
    // ph4: stage t+2: A0+A1 (A last read ph3); vmcnt
    if (pf) { STG(0, 0, 0, t + 2); STG(0, 0, 1, t + 2);
              STG(0, 1, 0, t + 2); STG(0, 1, 1, t + 2); }
    BARR; LGKM0; SB0;
    QUAD(1, 0);
    if (pf) { VMC8; } else { VMC0; }
    BARR;
    // ph5: (mh0,nh0) buf1
    RD_A(1, 0); RD_B(1);
    BARR; LGKM0; SB0;
    QUAD(0, 0);
    BARR;
    // ph6: stage t+3: B0'
    if (pf) { STG(1, 2, 0, t + 3); STG(1, 2, 1, t + 3); }
    BARR; LGKM0; SB0;
    QUAD(0, 1);
    BARR;
    // ph7: stage t+3: B1'
    RD_A(1, 1);
    if (pf) { STG(1, 3, 0, t + 3); STG(1, 3, 1, t + 3); }
    BARR; LGKM0; SB0;
    QUAD(1, 1);
    BARR;
    // ph8: stage t+3: A0'+A1'; vmcnt
    if (pf) { STG(1, 0, 0, t + 3); STG(1, 0, 1, t + 3);
              STG(1, 1, 0, t + 3); STG(1, 1, 1, t + 3); }
    BARR; LGKM0; SB0;
    QUAD(1, 0);
    if (pf) { VMC8; } else { VMC0; }
    BARR;
  }

#undef STG
#undef RD_A
#undef RD_B
#undef QUAD
#undef BARR
#undef LGKM0
#undef SB0
#undef VMC8
#undef VMC0

  // epilogue: frag D layout col = lane16, row = lg*4 + r
  const int row00 = bm * 256 + wm * 128, col00 = bn * 256 + wn * 64;
  if (EPI == 0) {
#pragma unroll
    for (int mf = 0; mf < 8; ++mf) {
#pragma unroll
      for (int nf = 0; nf < 4; ++nf) {
        const int col = col00 + nf * 16 + lane16;
        const float badd = BIAS ? bias[col] : 0.f;
        const int rb = row00 + mf * 16 + lg * 4;
#pragma unroll
        for (int r = 0; r < 4; ++r) {
          const float v = acc[mf][nf][r] + badd;
          if (OUTF32) ((float*)Cv)[(size_t)(rb + r) * N + col] = v;
          else        ((u16*)Cv)[(size_t)(rb + r) * N + col] = f2bf(v);
        }
      }
    }
  } else {
    const int mode = bn / 3;            // 0=q, 1=k, 2=v (768 = 3*256 aligned)
    const int chbase = col00 - mode * 768;
    if (mode < 2) {
      // transposed write: dst[b][h][d][n], n contiguous
      u16* dstm = mode == 0 ? qT : kT;
      const int b = row00 >> 10;        // whole 128-row half-tile in one b
      const int nbase = row00 & 1023;
#pragma unroll
      for (int nf = 0; nf < 4; ++nf) {
        const int ch = chbase + nf * 16 + lane16;       // 0..767
        const int h = (ch * 1366) >> 16;                // ch/48 (exact <768)
        const int d = ch - h * 48;
        u16* colp = dstm + (((size_t)b * 16 + h) * 48 + d) * 1024 + nbase;
#pragma unroll
        for (int mf = 0; mf < 8; ++mf) {
          const int n = mf * 16 + lg * 4;
          ushort4 pk;
          pk.x = f2bf(acc[mf][nf][0]); pk.y = f2bf(acc[mf][nf][1]);
          pk.z = f2bf(acc[mf][nf][2]); pk.w = f2bf(acc[mf][nf][3]);
          *(ushort4*)&colp[n] = pk;
        }
      }
    } else {
      // v: n-major [row][768]
#pragma unroll
      for (int mf = 0; mf < 8; ++mf) {
#pragma unroll
        for (int nf = 0; nf < 4; ++nf) {
          const int ch = chbase + nf * 16 + lane16;
          const int rb = row00 + mf * 16 + lg * 4;
#pragma unroll
          for (int r = 0; r < 4; ++r)
            vb[(size_t)(rb + r) * 768 + ch] = f2bf(acc[mf][nf][r]);
        }
      }
    }
  }
}

// ---------------------------------------------------------------------------
// BK=64 128x128 GEMM (round-8, known good) — projection GEMM.
// ---------------------------------------------------------------------------
template<int BIAS, int OUTF32>
__global__ __launch_bounds__(256)
void gemm_bt_kernel(const u16* __restrict__ A, const u16* __restrict__ B,
                    void* __restrict__ Cv, const float* __restrict__ bias,
                    int M, int N, int K, int nbn) {
  __shared__ alignas(16) u16 As[2][128][32];
  __shared__ alignas(16) u16 Bs[2][128][32];
  const int tid = threadIdx.x;
  const int l = tid & 63, w = tid >> 6;
  const int lane16 = l & 15, lg = l >> 4;
  const int wr = w >> 1, wc = w & 1;
  const int cpx = gridDim.x >> 3;
  const int swz = (blockIdx.x & 7) * cpx + (blockIdx.x >> 3);
  const int bm = swz / nbn, bn = swz - bm * nbn;

  const f32x4 zero = {0.f, 0.f, 0.f, 0.f};
  f32x4 acc[4][4];
#pragma unroll
  for (int i = 0; i < 4; ++i)
#pragma unroll
    for (int j = 0; j < 4; ++j) acc[i][j] = zero;

  const int r0 = tid >> 2, e0 = (tid & 3) * 8;
  const u16* Ap0 = A + (size_t)(bm * 128 + r0) * K + e0;
  const u16* Ap1 = A + (size_t)(bm * 128 + r0 + 64) * K + e0;
  const u16* Bp0 = B + (size_t)(bn * 128 + r0) * K + e0;
  const u16* Bp1 = B + (size_t)(bn * 128 + r0 + 64) * K + e0;

  for (int k0 = 0; k0 < K; k0 += 64) {
#pragma unroll
    for (int kk = 0; kk < 2; ++kk) {
      const int ko = k0 + kk * 32;
      GLD16(Ap0 + ko, (char*)&As[kk][0][0] + w * 1024);
      GLD16(Ap1 + ko, (char*)&As[kk][0][0] + 4096 + w * 1024);
      GLD16(Bp0 + ko, (char*)&Bs[kk][0][0] + w * 1024);
      GLD16(Bp1 + ko, (char*)&Bs[kk][0][0] + 4096 + w * 1024);
    }
    __syncthreads();

#pragma unroll
    for (int kk = 0; kk < 2; ++kk) {
      bf16x8 af[4], bfr[4];
#pragma unroll
      for (int i = 0; i < 4; ++i)
        af[i] = *(const bf16x8*)&As[kk][wr * 64 + i * 16 + lane16][lg * 8];
#pragma unroll
      for (int j = 0; j < 4; ++j)
        bfr[j] = *(const bf16x8*)&Bs[kk][wc * 64 + j * 16 + lane16][lg * 8];
#pragma unroll
      for (int i = 0; i < 4; ++i)
#pragma unroll
        for (int j = 0; j < 4; ++j)
          acc[i][j] = __builtin_amdgcn_mfma_f32_16x16x32_bf16(af[i], bfr[j], acc[i][j], 0, 0, 0);
    }
    __syncthreads();
  }

  const int row0 = bm * 128 + wr * 64, col0 = bn * 128 + wc * 64;
#pragma unroll
  for (int i = 0; i < 4; ++i) {
#pragma unroll
    for (int j = 0; j < 4; ++j) {
      const int col = col0 + j * 16 + lane16;
      const float badd = BIAS ? bias[col] : 0.f;
      const int rbase = row0 + i * 16 + lg * 4;
#pragma unroll
      for (int r = 0; r < 4; ++r) {
        const float v = acc[i][j][r] + badd;
        if (OUTF32) ((float*)Cv)[(size_t)(rbase + r) * N + col] = v;
        else        ((u16*)Cv)[(size_t)(rbase + r) * N + col] = f2bf(v);
      }
    }
  }
}

// ---------------------------------------------------------------------------
// XCA attention core v3. One block (4 waves) per (b,h).
// Inputs now pre-transposed: qT,kT[b][h][48][1024] (n contiguous) and
// v[b*1024+n][768]. Phase 2 is LDS-free and barrier-free: fragments load
// straight from global (16B/lane, 64B per 4-lane group).
// ---------------------------------------------------------------------------
__global__ __launch_bounds__(256)
void xca_attn_kernel(const u16* __restrict__ qT, const u16* __restrict__ kT,
                     const u16* __restrict__ vb,
                     const float* __restrict__ temperature,
                     u16* __restrict__ aout) {
  const int tid = threadIdx.x;
  const int l = tid & 63, w = tid >> 6;
  const int lane16 = l & 15, lg = l >> 4;
  const int bh = blockIdx.x, b = bh >> 4, h = bh & 15;

  __shared__ alignas(16) float attn_raw[48][48];   // 9 KB
  __shared__ alignas(16) u16 attn_bf[48][64];      // 6 KB
  __shared__ float sqs[2][48];
  __shared__ float rn[2][48];

  for (int i = tid; i < 48 * 48; i += 256) ((float*)attn_raw)[i] = 0.f;
  if (tid < 96) ((float*)sqs)[tid] = 0.f;
  __syncthreads();

  const f32x4 zero = {0.f, 0.f, 0.f, 0.f};
  f32x4 pqk[3][3], pqq[3], pkk[3];
#pragma unroll
  for (int i = 0; i < 3; ++i) {
    pqq[i] = zero; pkk[i] = zero;
#pragma unroll
    for (int j = 0; j < 3; ++j) pqk[i][j] = zero;
  }

  // ---- phase 2: QK^T + diag(QQ^T),diag(KK^T); direct global fragments ----
  const size_t hb = ((size_t)b * 16 + h) * 48 * 1024;
  const u16* qrow = qT + hb;
  const u16* krow = kT + hb;
  for (int s = 0; s < 8; ++s) {
    const int n0 = (s * 4 + w) * 32 + lg * 8;
    bf16x8 qf[3], kf[3];
#pragma unroll
    for (int i = 0; i < 3; ++i)
      qf[i] = *(const bf16x8*)&qrow[(i * 16 + lane16) * 1024 + n0];
#pragma unroll
    for (int j = 0; j < 3; ++j)
      kf[j] = *(const bf16x8*)&krow[(j * 16 + lane16) * 1024 + n0];
#pragma unroll
    for (int i = 0; i < 3; ++i)
#pragma unroll
      for (int j = 0; j < 3; ++j)
        pqk[i][j] = __builtin_amdgcn_mfma_f32_16x16x32_bf16(qf[i], kf[j], pqk[i][j], 0, 0, 0);
#pragma unroll
    for (int i = 0; i < 3; ++i) {
      pqq[i] = __builtin_amdgcn_mfma_f32_16x16x32_bf16(qf[i], qf[i], pqq[i], 0, 0, 0);
      pkk[i] = __builtin_amdgcn_mfma_f32_16x16x32_bf16(kf[i], kf[i], pkk[i], 0, 0, 0);
    }
  }

#pragma unroll
  for (int i = 0; i < 3; ++i)
#pragma unroll
    for (int j = 0; j < 3; ++j)
#pragma unroll
      for (int r = 0; r < 4; ++r)
        atomicAdd(&attn_raw[i * 16 + lg * 4 + r][j * 16 + lane16], pqk[i][j][r]);
  if (lg == (lane16 >> 2)) {
    const int r = lane16 & 3;
#pragma unroll
    for (int i = 0; i < 3; ++i) {
      atomicAdd(&sqs[0][i * 16 + lane16], pqq[i][r]);
      atomicAdd(&sqs[1][i * 16 + lane16], pkk[i][r]);
    }
  }
  __syncthreads();

  if (tid < 96) {
    const int m = tid / 48, d = tid % 48;
    rn[m][d] = 1.f / fmaxf(sqrtf(sqs[m][d]), 1e-12f);
  }
  __syncthreads();

  // ---- phase 3: row softmax, post-scaled by rnq[d]*rnk[e]*temp ----
  const float temp = temperature[h];
  if (tid < 48) {
    const float sr = rn[0][tid] * temp;
    float mx = -1e30f;
    for (int e = 0; e < 48; ++e)
      mx = fmaxf(mx, attn_raw[tid][e] * rn[1][e] * sr);
    float ssum = 0.f;
    for (int e = 0; e < 48; ++e) {
      const float p = __expf(attn_raw[tid][e] * rn[1][e] * sr - mx);
      attn_raw[tid][e] = p; ssum += p;
    }
    const float inv = 1.f / ssum;
    for (int e = 0; e < 48; ++e) attn_bf[tid][e] = f2bf(attn_raw[tid][e] * inv);
    for (int e = 48; e < 64; ++e) attn_bf[tid][e] = 0;
  }
  __syncthreads();

  // ---- phase 4: out = attn @ v, V fragments direct from global ----
  bf16x8 af2[3][2];
#pragma unroll
  for (int i = 0; i < 3; ++i)
#pragma unroll
    for (int ks = 0; ks < 2; ++ks)
      af2[i][ks] = *(const bf16x8*)&attn_bf[i * 16 + lane16][ks * 32 + lg * 8];

  const bf16x8 zf = {0, 0, 0, 0, 0, 0, 0, 0};
  for (int nf = 0; nf < 16; ++nf) {
    const int n0 = w * 256 + nf * 16;
    const u16* vsrc = vb + (size_t)(b * 1024 + n0 + lane16) * 768 + h * 48 + lg * 8;
    bf16x8 vf0 = *(const bf16x8*)vsrc;                        // e 0..31
    bf16x8 vf1 = (lg < 2) ? *(const bf16x8*)(vsrc + 32) : zf; // e 32..47
#pragma unroll
    for (int i = 0; i < 3; ++i) {
      f32x4 acc = zero;
      acc = __builtin_amdgcn_mfma_f32_16x16x32_bf16(af2[i][0], vf0, acc, 0, 0, 0);
      acc = __builtin_amdgcn_mfma_f32_16x16x32_bf16(af2[i][1], vf1, acc, 0, 0, 0);
      const size_t oo = (size_t)(b * 1024 + n0 + lane16) * 768 + h * 48 + i * 16 + lg * 4;
      ushort4 pack;
      pack.x = f2bf(acc[0]); pack.y = f2bf(acc[1]);
      pack.z = f2bf(acc[2]); pack.w = f2bf(acc[3]);
      *(ushort4*)&aout[oo] = pack;
    }
  }
}

// ---------------------------------------------------------------------------
extern "C" void kernel_launch(void* const* d_in, const int* in_sizes, int n_in,
                              void* d_out, int out_size, void* d_ws, size_t ws_size,
                              hipStream_t stream) {
  const float* x      = (const float*)d_in[0];  // [32768][768]
  const float* w_qkv  = (const float*)d_in[1];  // [2304][768]
  const float* w_proj = (const float*)d_in[2];  // [768][768]
  const float* b_proj = (const float*)d_in[3];  // [768]
  const float* temp   = (const float*)d_in[4];  // [16]
  float* out = (float*)d_out;                   // [32768][768]

  u16* x_bf = (u16*)d_out;                                  // dead until GEMM2
  char* ws = (char*)d_ws;
  u16* qT        = (u16*)ws;                                // 50.33 MB [B][H][48][1024]
  u16* kT        = (u16*)(ws + (size_t)50331648);           // 50.33 MB
  u16* vbuf      = (u16*)(ws + (size_t)100663296);          // 50.33 MB [B*N][768]
  u16* aoutb     = (u16*)(ws + (size_t)150994944);          // 50.33 MB
  u16* w_qkv_bf  = (u16*)(ws + (size_t)201326592);          // 3.54 MB
  u16* w_proj_bf = (u16*)(ws + (size_t)204865536);          // 1.18 MB

  dim3 blk(256);
  const int n0 = 32768 * 768, n1 = 2304 * 768, n2 = 768 * 768;
  cast3_f32_bf16_kernel<<<dim3((n0 + n1 + n2) / 1024), blk, 0, stream>>>(
      x, x_bf, n0, w_qkv, w_qkv_bf, n1, w_proj, w_proj_bf, n2);

  // qkv GEMM with split epilogue -> qT, kT, v. grid 128x9 = 1152; 6 iters.
  gemm8p_kernel<0, 0, 1><<<dim3(1152), dim3(512), 0, stream>>>(
      x_bf, w_qkv_bf, nullptr, nullptr, qT, kT, vbuf, 32768, 2304, 768, 9, 6);
  // attention core -> aoutb [B,N,C] bf16
  xca_attn_kernel<<<dim3(512), blk, 0, stream>>>(qT, kT, vbuf, temp, aoutb);
  // out = aoutb @ w_proj^T + b_proj : BK=64 128^2, 256x6 -> 1536 blocks
  gemm_bt_kernel<1, 1><<<dim3(1536), blk, 0, stream>>>(
      aoutb, w_proj_bf, out, b_proj, 32768, 768, 768, 6);
}